// Round 7
// baseline (768.245 us; speedup 1.0000x reference)
//
#include <hip/hip_runtime.h>
#include <math.h>

#define HD 64
#define FIN 512
#define NC 40

struct __align__(8) EdgeT { int s; float v; };

typedef __attribute__((ext_vector_type(8))) short bf16x8;
typedef __attribute__((ext_vector_type(8))) unsigned short u16x8;
typedef __attribute__((ext_vector_type(4))) float f32x4;

__device__ __forceinline__ float bf2f(ushort u) {
    return __uint_as_float(((unsigned int)u) << 16);
}
__device__ __forceinline__ ushort f2bf(float f) {
    unsigned int u = __float_as_uint(f);
    unsigned int r = (u + 0x7fffu + ((u >> 16) & 1u)) >> 16;   // RNE
    return (ushort)r;
}

// ---------------- graph preprocessing ----------------
// packed8[c*n+i]: bits[48:64) = edge count, bits[0:48) = fixed-point(2^-32) weighted degree.
// 8 shadow copies (c = edge_id & 7) cut atomic contention 8x. Fixed-point sum is order-exact.

__global__ __launch_bounds__(256) void initp_kernel(unsigned long long* packed8, int n) {
    int i = blockIdx.x * 256 + threadIdx.x;
    if (i < 8 * n) packed8[i] = (i < n) ? (1ULL << 32) : 0ULL;  // self-loop w=1 in copy 0
}

__global__ __launch_bounds__(256) void histp_kernel(const int* __restrict__ dst,
        const float* __restrict__ w, unsigned long long* packed8,
        ushort* __restrict__ rank, int E, int n) {
    int i = blockIdx.x * 256 + threadIdx.x;
    if (i < E) {
        int d = dst[i];
        int c = i & 7;
        unsigned long long add = (1ULL << 48) |
            (unsigned long long)(w[i] * 4294967296.0f);
        unsigned long long old = atomicAdd(&packed8[(size_t)c * n + d], add);
        rank[i] = (ushort)(old >> 48);
    }
}

// fused: dinv + copy-bases (8 bytes in uint2) + per-block count scan
__global__ __launch_bounds__(256) void post_kernel(const unsigned long long* __restrict__ packed8,
        float* __restrict__ dinv, uint2* __restrict__ cbase,
        int* __restrict__ row_ptr, int* __restrict__ bsums, int n) {
    __shared__ int s[256];
    const unsigned long long M = 0xFFFFFFFFFFFFULL;
    int t = threadIdx.x;
    int i = blockIdx.x * 256 + t;
    int cnt = 0;
    if (i < n) {
        int c[8];
        unsigned long long fx = 0;
#pragma unroll
        for (int k = 0; k < 8; ++k) {
            unsigned long long p = packed8[(size_t)k * n + i];
            c[k] = (int)(p >> 48);
            fx += (p & M);
        }
        float deg = (float)((double)fx * (1.0 / 4294967296.0));
        dinv[i] = rsqrtf(deg);                     // deg >= 1 (self-loop)
        int b = 0; uint lo = 0, hi = 0;
#pragma unroll
        for (int k = 0; k < 4; ++k) { lo |= ((uint)b) << (8 * k); b += c[k]; }
#pragma unroll
        for (int k = 0; k < 4; ++k) { hi |= ((uint)b) << (8 * k); b += c[4 + k]; }
        cbase[i] = make_uint2(lo, hi);
        cnt = b;
    }
    s[t] = cnt; __syncthreads();
    for (int off = 1; off < 256; off <<= 1) {
        int u = (t >= off) ? s[t - off] : 0;
        __syncthreads();
        s[t] += u;
        __syncthreads();
    }
    if (i < n) row_ptr[i] = s[t] - cnt;
    if (t == 255) bsums[blockIdx.x] = s[255];
}

__global__ __launch_bounds__(512) void scan_top_kernel(int* bsums, int nb) {
    __shared__ int s[512];
    int t = threadIdx.x;
    int v = (t < nb) ? bsums[t] : 0;
    s[t] = v; __syncthreads();
    for (int off = 1; off < 512; off <<= 1) {
        int u = (t >= off) ? s[t - off] : 0;
        __syncthreads();
        s[t] += u;
        __syncthreads();
    }
    if (t < nb) bsums[t] = s[t] - v;
}

__global__ __launch_bounds__(256) void scan_add_kernel(int* __restrict__ row_ptr,
        const int* __restrict__ bsums, int n, int E) {
    int i = blockIdx.x * 256 + threadIdx.x;
    if (i < n) row_ptr[i] += bsums[blockIdx.x];
    if (i == 0) row_ptr[n] = E;
}

__global__ __launch_bounds__(256) void scatter_kernel(const int* __restrict__ src,
        const int* __restrict__ dst, const float* __restrict__ w,
        const float* __restrict__ dinv, const int* __restrict__ row_ptr,
        const uint2* __restrict__ cbase, const ushort* __restrict__ rank,
        EdgeT* __restrict__ ed, int E) {
    int i = blockIdx.x * 256 + threadIdx.x;
    if (i < E) {
        int s = src[i], d = dst[i];
        int c = i & 7;
        uint2 cb = cbase[d];
        int base = (int)(((c < 4) ? (cb.x >> (8 * c)) : (cb.y >> (8 * (c - 4)))) & 0xffu);
        int pos = row_ptr[d] + base + (int)rank[i];
        EdgeT e; e.s = s; e.v = dinv[s] * w[i] * dinv[d];
        ed[pos] = e;
    }
}

// setup: W_out zero-pad + b_out pad + W_in -> bf16 fragment-major
// Wf[((c*4+t)*64+l)*8+j] = W_in[c*32+8*(l>>4)+j][t*16+(l&15)]
__global__ __launch_bounds__(256) void setup_kernel(const float* __restrict__ W,
        ushort* __restrict__ Wf, const float* __restrict__ Wo,
        const float* __restrict__ bo, float* __restrict__ Wo_pad,
        float* __restrict__ bo_pad) {
    int i = blockIdx.x * 256 + threadIdx.x;
    if (i < FIN * HD) {
        int j = i & 7;
        int l = (i >> 3) & 63;
        int t = (i >> 9) & 3;
        int c = i >> 11;
        int k = c * 32 + ((l >> 4) * 8) + j;
        int col = t * 16 + (l & 15);
        Wf[i] = f2bf(W[k * HD + col]);
    }
    if (i < HD * HD) {
        int k = i >> 6, c2 = i & 63;
        Wo_pad[i] = (c2 < NC) ? Wo[k * NC + c2] : 0.f;
    }
    if (i < HD) bo_pad[i] = (i < NC) ? bo[i] : 0.f;
}

// ---------------- proj (MFMA): h0 = relu(x @ W_in + b_in) -> bf16 ----------------

__global__ __launch_bounds__(256) void projm_kernel(const float* __restrict__ x,
        const ushort* __restrict__ Wf, const float* __restrict__ bias,
        ushort* __restrict__ h0, int n) {
    const int lane = threadIdx.x & 63;
    const int wave = threadIdx.x >> 6;
    const int row = lane & 15;
    const int g = lane >> 4;
    const int base = blockIdx.x * 128 + wave * 32;

    f32x4 acc[2][4];
#pragma unroll
    for (int m = 0; m < 2; ++m)
#pragma unroll
        for (int t = 0; t < 4; ++t) acc[m][t] = (f32x4){0.f, 0.f, 0.f, 0.f};

    for (int c = 0; c < 16; ++c) {
        bf16x8 afr[2];
#pragma unroll
        for (int m = 0; m < 2; ++m) {
            int node = base + m * 16 + row;
            if (node >= n) node = n - 1;
            const float* p = x + (size_t)node * FIN + c * 32 + g * 8;
            float4 v0 = *(const float4*)p;
            float4 v1 = *(const float4*)(p + 4);
            afr[m][0] = (short)f2bf(v0.x); afr[m][1] = (short)f2bf(v0.y);
            afr[m][2] = (short)f2bf(v0.z); afr[m][3] = (short)f2bf(v0.w);
            afr[m][4] = (short)f2bf(v1.x); afr[m][5] = (short)f2bf(v1.y);
            afr[m][6] = (short)f2bf(v1.z); afr[m][7] = (short)f2bf(v1.w);
        }
#pragma unroll
        for (int t = 0; t < 4; ++t) {
            bf16x8 bfr = *(const bf16x8*)(Wf + ((size_t)(c * 4 + t) * 64 + lane) * 8);
            acc[0][t] = __builtin_amdgcn_mfma_f32_16x16x32_bf16(afr[0], bfr, acc[0][t], 0, 0, 0);
            acc[1][t] = __builtin_amdgcn_mfma_f32_16x16x32_bf16(afr[1], bfr, acc[1][t], 0, 0, 0);
        }
    }

    float bj[4];
#pragma unroll
    for (int t = 0; t < 4; ++t) bj[t] = bias[t * 16 + row];
#pragma unroll
    for (int m = 0; m < 2; ++m)
#pragma unroll
        for (int r = 0; r < 4; ++r) {
            int node = base + m * 16 + g * 4 + r;
            if (node < n) {
#pragma unroll
                for (int t = 0; t < 4; ++t) {
                    float v = fmaxf(acc[m][t][r] + bj[t], 0.f);
                    h0[(size_t)node * HD + t * 16 + row] = f2bf(v);
                }
            }
        }
}

// ---------------- fused layer: SpMM + residual + 64x64 GEMM + relu ----------------
// Wave-autonomous: each wave owns a 16-node tile. Gather: 8 lanes/node, 16B loads.
// sup kept in f32 (LDS) through the GEMM; only h_out is rounded to bf16.

__global__ __launch_bounds__(256) void layerf_kernel(const ushort* __restrict__ h_in,
        const ushort* __restrict__ h0, ushort* __restrict__ h_out,
        const float* __restrict__ W, const float* __restrict__ dinv,
        const int* __restrict__ row_ptr, const EdgeT* __restrict__ ed,
        float beta, int n) {
    __shared__ float Wl[HD * HD];          // 16 KB
    __shared__ float Sf[4][16 * 68];       // 17 KB, per-wave sup slice
#pragma unroll
    for (int p = 0; p < 4; ++p) {
        int i = threadIdx.x + p * 256;
        *(float4*)(Wl + i * 4) = *(const float4*)(W + i * 4);
    }
    __syncthreads();

    const int lane = threadIdx.x & 63;
    const int wave = threadIdx.x >> 6;
    const int g = lane >> 3;               // node slot 0..7
    const int fl = (lane & 7) * 8;         // feature offset
    float* S = Sf[wave];
    const int tbase = (blockIdx.x * 4 + wave) * 16;

    // ---- gather phase: 2 passes of 8 nodes ----
#pragma unroll
    for (int p = 0; p < 2; ++p) {
        int node = tbase + p * 8 + g;
        int nc = (node < n) ? node : n - 1;
        float di = dinv[nc];
        float sw = di * di;
        float a[8], b[8];
        u16x8 us = *(const u16x8*)(h_in + (size_t)nc * HD + fl);
#pragma unroll
        for (int j = 0; j < 8; ++j) { a[j] = sw * bf2f((ushort)us[j]); b[j] = 0.f; }
        int e = row_ptr[nc], end = row_ptr[nc + 1];
        for (; e + 4 <= end; e += 4) {
            EdgeT E0 = ed[e], E1 = ed[e + 1], E2 = ed[e + 2], E3 = ed[e + 3];
            u16x8 u0 = *(const u16x8*)(h_in + (size_t)E0.s * HD + fl);
            u16x8 u1 = *(const u16x8*)(h_in + (size_t)E1.s * HD + fl);
            u16x8 u2 = *(const u16x8*)(h_in + (size_t)E2.s * HD + fl);
            u16x8 u3 = *(const u16x8*)(h_in + (size_t)E3.s * HD + fl);
#pragma unroll
            for (int j = 0; j < 8; ++j) {
                a[j] = fmaf(E0.v, bf2f((ushort)u0[j]), a[j]);
                b[j] = fmaf(E1.v, bf2f((ushort)u1[j]), b[j]);
                a[j] = fmaf(E2.v, bf2f((ushort)u2[j]), a[j]);
                b[j] = fmaf(E3.v, bf2f((ushort)u3[j]), b[j]);
            }
        }
        for (; e < end; ++e) {
            EdgeT E0 = ed[e];
            u16x8 u0 = *(const u16x8*)(h_in + (size_t)E0.s * HD + fl);
#pragma unroll
            for (int j = 0; j < 8; ++j) a[j] = fmaf(E0.v, bf2f((ushort)u0[j]), a[j]);
        }
        u16x8 uh = *(const u16x8*)(h0 + (size_t)nc * HD + fl);
        float r[8];
#pragma unroll
        for (int j = 0; j < 8; ++j)
            r[j] = fmaf(0.9f, a[j] + b[j], 0.1f * bf2f((ushort)uh[j]));
        *(float4*)(S + (p * 8 + g) * 68 + fl)     = *(float4*)&r[0];
        *(float4*)(S + (p * 8 + g) * 68 + fl + 4) = *(float4*)&r[4];
    }

    asm volatile("s_waitcnt lgkmcnt(0)" ::: "memory");
    __builtin_amdgcn_wave_barrier();
    __builtin_amdgcn_sched_barrier(0);

    // ---- GEMM phase: 16 nodes x 64 cols, 4x4 per lane ----
    const int tx = lane & 15;
    const int ty = lane >> 4;
    float acc[4][4];
#pragma unroll
    for (int i = 0; i < 4; ++i)
#pragma unroll
        for (int j = 0; j < 4; ++j) acc[i][j] = 0.f;

#pragma unroll
    for (int kk = 0; kk < 64; kk += 4) {
        float4 a4[4];
#pragma unroll
        for (int i = 0; i < 4; ++i)
            a4[i] = *(const float4*)(S + (ty * 4 + i) * 68 + kk);
#pragma unroll
        for (int k2 = 0; k2 < 4; ++k2) {
            float w[4];
            *(float4*)w = *(const float4*)(Wl + (kk + k2) * 64 + tx * 4);
#pragma unroll
            for (int i = 0; i < 4; ++i) {
                float a = ((const float*)&a4[i])[k2];
#pragma unroll
                for (int j = 0; j < 4; ++j) acc[i][j] = fmaf(a, w[j], acc[i][j]);
            }
        }
    }

    const float ombeta = 1.f - beta;
#pragma unroll
    for (int i = 0; i < 4; ++i) {
        int node = tbase + ty * 4 + i;
        if (node < n) {
            ushort4 r;
            float s0 = S[(ty * 4 + i) * 68 + tx * 4 + 0];
            float s1 = S[(ty * 4 + i) * 68 + tx * 4 + 1];
            float s2 = S[(ty * 4 + i) * 68 + tx * 4 + 2];
            float s3 = S[(ty * 4 + i) * 68 + tx * 4 + 3];
            r.x = f2bf(fmaxf(fmaf(beta, acc[i][0], ombeta * s0), 0.f));
            r.y = f2bf(fmaxf(fmaf(beta, acc[i][1], ombeta * s1), 0.f));
            r.z = f2bf(fmaxf(fmaf(beta, acc[i][2], ombeta * s2), 0.f));
            r.w = f2bf(fmaxf(fmaf(beta, acc[i][3], ombeta * s3), 0.f));
            *(ushort4*)(h_out + (size_t)node * HD + tx * 4) = r;
        }
    }
}

// ---------------- output GEMM + log_softmax (bf16 A, fp32 W, K=64) ----------------

__global__ __launch_bounds__(256) void outg_kernel(const ushort* __restrict__ A,
        const float* __restrict__ W, const float* __restrict__ bias,
        float* __restrict__ outp, int n) {
    __shared__ float Af[64 * 68];
    __shared__ float Wl[64 * 64];
    const int tid = threadIdx.x;
    const int tx = tid & 15;
    const int ty = tid >> 4;
    const int base = blockIdx.x * 64;
    const int kq = (tid & 15) * 4;
    const int rw = tid >> 4;

#pragma unroll
    for (int p = 0; p < 4; ++p) {
        int row = rw + p * 16;
        int ng = base + row; if (ng >= n) ng = n - 1;
        ushort4 u = *(const ushort4*)(A + (size_t)ng * HD + kq);
        Af[row * 68 + kq + 0] = bf2f(u.x);
        Af[row * 68 + kq + 1] = bf2f(u.y);
        Af[row * 68 + kq + 2] = bf2f(u.z);
        Af[row * 68 + kq + 3] = bf2f(u.w);
        *(float4*)(Wl + row * 64 + kq) =
            *(const float4*)(W + (size_t)row * HD + kq);
    }
    __syncthreads();

    float acc[4][4];
#pragma unroll
    for (int i = 0; i < 4; ++i)
#pragma unroll
        for (int j = 0; j < 4; ++j) acc[i][j] = 0.f;

#pragma unroll
    for (int kk = 0; kk < 64; kk += 4) {
        float4 a4[4];
#pragma unroll
        for (int i = 0; i < 4; ++i)
            a4[i] = *(const float4*)(Af + (ty * 4 + i) * 68 + kk);
#pragma unroll
        for (int k2 = 0; k2 < 4; ++k2) {
            float w[4];
            *(float4*)w = *(const float4*)(Wl + (kk + k2) * 64 + tx * 4);
#pragma unroll
            for (int i = 0; i < 4; ++i) {
                float a = ((const float*)&a4[i])[k2];
#pragma unroll
                for (int j = 0; j < 4; ++j) acc[i][j] = fmaf(a, w[j], acc[i][j]);
            }
        }
    }

    float b[4];
#pragma unroll
    for (int j = 0; j < 4; ++j) b[j] = bias[tx * 4 + j];
    const bool valid = (tx < 10);
#pragma unroll
    for (int i = 0; i < 4; ++i) {
        float lo[4];
        float m = -3.0e38f;
#pragma unroll
        for (int j = 0; j < 4; ++j) {
            lo[j] = acc[i][j] + b[j];
            if (valid) m = fmaxf(m, lo[j]);
        }
#pragma unroll
        for (int off = 1; off < 16; off <<= 1)
            m = fmaxf(m, __shfl_xor(m, off, 64));
        float s = 0.f;
        if (valid) {
#pragma unroll
            for (int j = 0; j < 4; ++j) s += __expf(lo[j] - m);
        }
#pragma unroll
        for (int off = 1; off < 16; off <<= 1)
            s += __shfl_xor(s, off, 64);
        float lse = __logf(s);
        int ng = base + ty * 4 + i;
        if (ng < n && valid) {
            float4 r;
            r.x = lo[0] - m - lse; r.y = lo[1] - m - lse;
            r.z = lo[2] - m - lse; r.w = lo[3] - m - lse;
            *(float4*)(outp + (size_t)ng * NC + tx * 4) = r;
        }
    }
}

// ---------------- launch ----------------

extern "C" void kernel_launch(void* const* d_in, const int* in_sizes, int n_in,
                              void* d_out, int out_size, void* d_ws, size_t ws_size,
                              hipStream_t stream) {
    const float* x        = (const float*)d_in[0];
    const int*   eidx     = (const int*)d_in[1];
    const float* ew       = (const float*)d_in[2];
    const float* W_in     = (const float*)d_in[3];
    const float* b_in     = (const float*)d_in[4];
    const float* W_layers = (const float*)d_in[5];
    const float* W_out    = (const float*)d_in[6];
    const float* b_out    = (const float*)d_in[7];
    float* out = (float*)d_out;

    const int N = in_sizes[0] / FIN;
    const int E = in_sizes[2];
    const int L = in_sizes[5] / (HD * HD);
    const int* src = eidx;
    const int* dst = eidx + E;

    size_t off = 0;
    auto carve = [&](size_t bytes) {
        void* p = (char*)d_ws + off;
        off += (bytes + 255) & ~(size_t)255;
        return p;
    };
    unsigned long long* packed8 = (unsigned long long*)carve((size_t)N * 8 * 8);
    float*  dinv    = (float*)carve((size_t)N * 4);
    uint2*  cbase   = (uint2*)carve((size_t)N * 8);
    int*    row_ptr = (int*)  carve((size_t)(N + 1) * 4);
    int*    bsums   = (int*)  carve(512 * 4);
    float*  Wo_pad  = (float*)carve((size_t)HD * HD * 4);
    float*  bo_pad  = (float*)carve((size_t)HD * 4);
    ushort* Wf      = (ushort*)carve((size_t)FIN * HD * 2);
    ushort* rank    = (ushort*)carve((size_t)E * 2);
    EdgeT*  ed      = (EdgeT*)carve((size_t)E * 8);
    ushort* h0      = (ushort*)carve((size_t)N * HD * 2);
    ushort* hA      = (ushort*)carve((size_t)N * HD * 2);
    ushort* hB      = (ushort*)carve((size_t)N * HD * 2);
    (void)ws_size;

    const int NB = (N + 255) / 256;
    const int EB = (E + 255) / 256;

    initp_kernel<<<(8 * N + 255) / 256, 256, 0, stream>>>(packed8, N);
    histp_kernel<<<EB, 256, 0, stream>>>(dst, ew, packed8, rank, E, N);
    post_kernel<<<NB, 256, 0, stream>>>(packed8, dinv, cbase, row_ptr, bsums, N);
    scan_top_kernel<<<1, 512, 0, stream>>>(bsums, NB);
    scan_add_kernel<<<NB, 256, 0, stream>>>(row_ptr, bsums, N, E);
    scatter_kernel<<<EB, 256, 0, stream>>>(src, dst, ew, dinv, row_ptr, cbase, rank, ed, E);
    setup_kernel<<<(FIN * HD + 255) / 256, 256, 0, stream>>>(W_in, Wf, W_out, b_out,
                                                             Wo_pad, bo_pad);

    projm_kernel<<<(N + 127) / 128, 256, 0, stream>>>(x, Wf, b_in, h0, N);

    const int NT = (N + 63) / 64;
    const ushort* cur = h0;
    ushort* bufs[2] = { hA, hB };
    for (int i = 0; i < L; ++i) {
        float beta = logf(0.5f / (float)(i + 1) + 1.0f);
        ushort* nxt = bufs[i & 1];
        layerf_kernel<<<NT, 256, 0, stream>>>(cur, h0, nxt, W_layers + (size_t)i * HD * HD,
                                              dinv, row_ptr, ed, beta, N);
        cur = nxt;
    }

    outg_kernel<<<NT, 256, 0, stream>>>(cur, Wo_pad, bo_pad, out, N);
}

// Round 8
// 562.458 us; speedup vs baseline: 1.3659x; 1.3659x over previous
//
#include <hip/hip_runtime.h>
#include <math.h>

#define HD 64
#define FIN 512
#define NC 40

struct __align__(8) EdgeT { int s; float v; };

typedef __attribute__((ext_vector_type(8))) short bf16x8;
typedef __attribute__((ext_vector_type(4))) float f32x4;

__device__ __forceinline__ float bf2f(ushort u) {
    return __uint_as_float(((unsigned int)u) << 16);
}
__device__ __forceinline__ ushort f2bf(float f) {
    unsigned int u = __float_as_uint(f);
    unsigned int r = (u + 0x7fffu + ((u >> 16) & 1u)) >> 16;   // RNE
    return (ushort)r;
}

// ---------------- graph preprocessing ----------------
// packed8[c*n+i]: bits[48:64) = edge count, bits[0:48) = fixed-point(2^-32) weighted degree.
// 8 shadow copies (c = edge_id & 7) cut atomic contention 8x. Fixed-point sum is order-exact.

__global__ __launch_bounds__(256) void initp_kernel(unsigned long long* packed8, int n) {
    int i = blockIdx.x * 256 + threadIdx.x;
    if (i < 8 * n) packed8[i] = (i < n) ? (1ULL << 32) : 0ULL;  // self-loop w=1 in copy 0
}

__global__ __launch_bounds__(256) void histp_kernel(const int* __restrict__ dst,
        const float* __restrict__ w, unsigned long long* packed8,
        ushort* __restrict__ rank, int E, int n) {
    int i = blockIdx.x * 256 + threadIdx.x;
    if (i < E) {
        int d = dst[i];
        int c = i & 7;
        unsigned long long add = (1ULL << 48) |
            (unsigned long long)(w[i] * 4294967296.0f);
        unsigned long long old = atomicAdd(&packed8[(size_t)c * n + d], add);
        rank[i] = (ushort)(old >> 48);
    }
}

// fused: dinv + copy-bases (8 bytes in uint2) + per-block count scan
__global__ __launch_bounds__(256) void post_kernel(const unsigned long long* __restrict__ packed8,
        float* __restrict__ dinv, uint2* __restrict__ cbase,
        int* __restrict__ row_ptr, int* __restrict__ bsums, int n) {
    __shared__ int s[256];
    const unsigned long long M = 0xFFFFFFFFFFFFULL;
    int t = threadIdx.x;
    int i = blockIdx.x * 256 + t;
    int cnt = 0;
    if (i < n) {
        int c[8];
        unsigned long long fx = 0;
#pragma unroll
        for (int k = 0; k < 8; ++k) {
            unsigned long long p = packed8[(size_t)k * n + i];
            c[k] = (int)(p >> 48);
            fx += (p & M);
        }
        float deg = (float)((double)fx * (1.0 / 4294967296.0));
        dinv[i] = rsqrtf(deg);                     // deg >= 1 (self-loop)
        int b = 0; uint lo = 0, hi = 0;
#pragma unroll
        for (int k = 0; k < 4; ++k) { lo |= ((uint)b) << (8 * k); b += c[k]; }
#pragma unroll
        for (int k = 0; k < 4; ++k) { hi |= ((uint)b) << (8 * k); b += c[4 + k]; }
        cbase[i] = make_uint2(lo, hi);
        cnt = b;
    }
    s[t] = cnt; __syncthreads();
    for (int off = 1; off < 256; off <<= 1) {
        int u = (t >= off) ? s[t - off] : 0;
        __syncthreads();
        s[t] += u;
        __syncthreads();
    }
    if (i < n) row_ptr[i] = s[t] - cnt;
    if (t == 255) bsums[blockIdx.x] = s[255];
}

__global__ __launch_bounds__(512) void scan_top_kernel(int* bsums, int nb) {
    __shared__ int s[512];
    int t = threadIdx.x;
    int v = (t < nb) ? bsums[t] : 0;
    s[t] = v; __syncthreads();
    for (int off = 1; off < 512; off <<= 1) {
        int u = (t >= off) ? s[t - off] : 0;
        __syncthreads();
        s[t] += u;
        __syncthreads();
    }
    if (t < nb) bsums[t] = s[t] - v;
}

__global__ __launch_bounds__(256) void scan_add_kernel(int* __restrict__ row_ptr,
        const int* __restrict__ bsums, int n, int E) {
    int i = blockIdx.x * 256 + threadIdx.x;
    if (i < n) row_ptr[i] += bsums[blockIdx.x];
    if (i == 0) row_ptr[n] = E;
}

__global__ __launch_bounds__(256) void scatter_kernel(const int* __restrict__ src,
        const int* __restrict__ dst, const float* __restrict__ w,
        const float* __restrict__ dinv, const int* __restrict__ row_ptr,
        const uint2* __restrict__ cbase, const ushort* __restrict__ rank,
        EdgeT* __restrict__ ed, int E) {
    int i = blockIdx.x * 256 + threadIdx.x;
    if (i < E) {
        int s = src[i], d = dst[i];
        int c = i & 7;
        uint2 cb = cbase[d];
        int base = (int)(((c < 4) ? (cb.x >> (8 * c)) : (cb.y >> (8 * (c - 4)))) & 0xffu);
        int pos = row_ptr[d] + base + (int)rank[i];
        EdgeT e; e.s = s; e.v = dinv[s] * w[i] * dinv[d];
        ed[pos] = e;
    }
}

// setup: W_out zero-pad + b_out pad + W_in -> bf16 fragment-major
// Wf[((c*4+t)*64+l)*8+j] = W_in[c*32+8*(l>>4)+j][t*16+(l&15)]
__global__ __launch_bounds__(256) void setup_kernel(const float* __restrict__ W,
        ushort* __restrict__ Wf, const float* __restrict__ Wo,
        const float* __restrict__ bo, float* __restrict__ Wo_pad,
        float* __restrict__ bo_pad) {
    int i = blockIdx.x * 256 + threadIdx.x;
    if (i < FIN * HD) {
        int j = i & 7;
        int l = (i >> 3) & 63;
        int t = (i >> 9) & 3;
        int c = i >> 11;
        int k = c * 32 + ((l >> 4) * 8) + j;
        int col = t * 16 + (l & 15);
        Wf[i] = f2bf(W[k * HD + col]);
    }
    if (i < HD * HD) {
        int k = i >> 6, c2 = i & 63;
        Wo_pad[i] = (c2 < NC) ? Wo[k * NC + c2] : 0.f;
    }
    if (i < HD) bo_pad[i] = (i < NC) ? bo[i] : 0.f;
}

// ---------------- SpMM v3 (bf16 h, 4 nodes/wave): sup = 0.9*(Ahat@h_in) + 0.1*h0 ----
// 16 lanes per node; lane owns feature quad (lane&15)*4.

__global__ __launch_bounds__(256) void spmm_kernel(const ushort* __restrict__ h_in,
        const ushort* __restrict__ h0, ushort* __restrict__ sup,
        const float* __restrict__ dinv, const int* __restrict__ row_ptr,
        const EdgeT* __restrict__ ed, int n) {
    const int lane = threadIdx.x & 63;
    const int q = lane >> 4;
    const int fl = (lane & 15) * 4;
    int wid = (blockIdx.x * 256 + threadIdx.x) >> 6;
    int nw = (gridDim.x * 256) >> 6;
    int nquads = (n + 3) >> 2;
    for (int quad = wid; quad < nquads; quad += nw) {
        int node = quad * 4 + q;
        bool valid = node < n;
        int nc = valid ? node : n - 1;
        float di = dinv[nc];
        float sw = di * di;
        ushort4 us = *(const ushort4*)(h_in + (size_t)nc * HD + fl);
        float a0[4], a1[4] = {0,0,0,0}, a2[4] = {0,0,0,0}, a3[4] = {0,0,0,0};
        a0[0] = sw * bf2f(us.x); a0[1] = sw * bf2f(us.y);
        a0[2] = sw * bf2f(us.z); a0[3] = sw * bf2f(us.w);
        int e = row_ptr[nc], end = row_ptr[nc + 1];
        for (; e + 4 <= end; e += 4) {
            EdgeT E0 = ed[e], E1 = ed[e + 1], E2 = ed[e + 2], E3 = ed[e + 3];
            ushort4 u0 = *(const ushort4*)(h_in + (size_t)E0.s * HD + fl);
            ushort4 u1 = *(const ushort4*)(h_in + (size_t)E1.s * HD + fl);
            ushort4 u2 = *(const ushort4*)(h_in + (size_t)E2.s * HD + fl);
            ushort4 u3 = *(const ushort4*)(h_in + (size_t)E3.s * HD + fl);
            a0[0] = fmaf(E0.v, bf2f(u0.x), a0[0]); a0[1] = fmaf(E0.v, bf2f(u0.y), a0[1]);
            a0[2] = fmaf(E0.v, bf2f(u0.z), a0[2]); a0[3] = fmaf(E0.v, bf2f(u0.w), a0[3]);
            a1[0] = fmaf(E1.v, bf2f(u1.x), a1[0]); a1[1] = fmaf(E1.v, bf2f(u1.y), a1[1]);
            a1[2] = fmaf(E1.v, bf2f(u1.z), a1[2]); a1[3] = fmaf(E1.v, bf2f(u1.w), a1[3]);
            a2[0] = fmaf(E2.v, bf2f(u2.x), a2[0]); a2[1] = fmaf(E2.v, bf2f(u2.y), a2[1]);
            a2[2] = fmaf(E2.v, bf2f(u2.z), a2[2]); a2[3] = fmaf(E2.v, bf2f(u2.w), a2[3]);
            a3[0] = fmaf(E3.v, bf2f(u3.x), a3[0]); a3[1] = fmaf(E3.v, bf2f(u3.y), a3[1]);
            a3[2] = fmaf(E3.v, bf2f(u3.z), a3[2]); a3[3] = fmaf(E3.v, bf2f(u3.w), a3[3]);
        }
        for (; e < end; ++e) {
            EdgeT E0 = ed[e];
            ushort4 u0 = *(const ushort4*)(h_in + (size_t)E0.s * HD + fl);
            a0[0] = fmaf(E0.v, bf2f(u0.x), a0[0]); a0[1] = fmaf(E0.v, bf2f(u0.y), a0[1]);
            a0[2] = fmaf(E0.v, bf2f(u0.z), a0[2]); a0[3] = fmaf(E0.v, bf2f(u0.w), a0[3]);
        }
        if (valid) {
            ushort4 uh = *(const ushort4*)(h0 + (size_t)nc * HD + fl);
            ushort4 r;
            r.x = f2bf(fmaf(0.9f, (a0[0] + a1[0]) + (a2[0] + a3[0]), 0.1f * bf2f(uh.x)));
            r.y = f2bf(fmaf(0.9f, (a0[1] + a1[1]) + (a2[1] + a3[1]), 0.1f * bf2f(uh.y)));
            r.z = f2bf(fmaf(0.9f, (a0[2] + a1[2]) + (a2[2] + a3[2]), 0.1f * bf2f(uh.z)));
            r.w = f2bf(fmaf(0.9f, (a0[3] + a1[3]) + (a2[3] + a3[3]), 0.1f * bf2f(uh.w)));
            *(ushort4*)(sup + (size_t)node * HD + fl) = r;
        }
    }
}

// ---------------- proj (MFMA): h0 = relu(x @ W_in + b_in) -> bf16 ----------------
// wave: 32 nodes (2 M-frags) x 64 cols (4 N-frags); block = 4 waves = 128 nodes.

__global__ __launch_bounds__(256) void projm_kernel(const float* __restrict__ x,
        const ushort* __restrict__ Wf, const float* __restrict__ bias,
        ushort* __restrict__ h0, int n) {
    const int lane = threadIdx.x & 63;
    const int wave = threadIdx.x >> 6;
    const int row = lane & 15;
    const int g = lane >> 4;
    const int base = blockIdx.x * 128 + wave * 32;

    f32x4 acc[2][4];
#pragma unroll
    for (int m = 0; m < 2; ++m)
#pragma unroll
        for (int t = 0; t < 4; ++t) acc[m][t] = (f32x4){0.f, 0.f, 0.f, 0.f};

    for (int c = 0; c < 16; ++c) {
        bf16x8 afr[2];
#pragma unroll
        for (int m = 0; m < 2; ++m) {
            int node = base + m * 16 + row;
            if (node >= n) node = n - 1;
            const float* p = x + (size_t)node * FIN + c * 32 + g * 8;
            float4 v0 = *(const float4*)p;
            float4 v1 = *(const float4*)(p + 4);
            afr[m][0] = (short)f2bf(v0.x); afr[m][1] = (short)f2bf(v0.y);
            afr[m][2] = (short)f2bf(v0.z); afr[m][3] = (short)f2bf(v0.w);
            afr[m][4] = (short)f2bf(v1.x); afr[m][5] = (short)f2bf(v1.y);
            afr[m][6] = (short)f2bf(v1.z); afr[m][7] = (short)f2bf(v1.w);
        }
#pragma unroll
        for (int t = 0; t < 4; ++t) {
            bf16x8 bfr = *(const bf16x8*)(Wf + ((size_t)(c * 4 + t) * 64 + lane) * 8);
            acc[0][t] = __builtin_amdgcn_mfma_f32_16x16x32_bf16(afr[0], bfr, acc[0][t], 0, 0, 0);
            acc[1][t] = __builtin_amdgcn_mfma_f32_16x16x32_bf16(afr[1], bfr, acc[1][t], 0, 0, 0);
        }
    }

    float bj[4];
#pragma unroll
    for (int t = 0; t < 4; ++t) bj[t] = bias[t * 16 + row];
#pragma unroll
    for (int m = 0; m < 2; ++m)
#pragma unroll
        for (int r = 0; r < 4; ++r) {
            int node = base + m * 16 + g * 4 + r;
            if (node < n) {
#pragma unroll
                for (int t = 0; t < 4; ++t) {
                    float v = fmaxf(acc[m][t][r] + bj[t], 0.f);
                    h0[(size_t)node * HD + t * 16 + row] = f2bf(v);
                }
            }
        }
}

// ---------------- layer / output GEMM over bf16 A, fp32 W, K=64 ----------------
// MODE 1: relu(beta*acc + (1-beta)*A) -> C (bf16, in-place safe)
// MODE 2: log_softmax(acc + bias) over first NC cols -> outp fp32

template<int MODE>
__global__ __launch_bounds__(256) void lgemm_kernel(const ushort* __restrict__ A,
        const float* __restrict__ W, const float* __restrict__ bias,
        ushort* __restrict__ C, float* __restrict__ outp, int n, float beta) {
    __shared__ float Af[64 * 68];
    __shared__ float Wl[64 * 64];
    const int tid = threadIdx.x;
    const int tx = tid & 15;
    const int ty = tid >> 4;
    const int base = blockIdx.x * 64;
    const int kq = (tid & 15) * 4;
    const int rw = tid >> 4;

#pragma unroll
    for (int p = 0; p < 4; ++p) {
        int row = rw + p * 16;
        int ng = base + row; if (ng >= n) ng = n - 1;
        ushort4 u = *(const ushort4*)(A + (size_t)ng * HD + kq);
        Af[row * 68 + kq + 0] = bf2f(u.x);
        Af[row * 68 + kq + 1] = bf2f(u.y);
        Af[row * 68 + kq + 2] = bf2f(u.z);
        Af[row * 68 + kq + 3] = bf2f(u.w);
        *(float4*)(Wl + row * 64 + kq) =
            *(const float4*)(W + (size_t)row * HD + kq);
    }
    __syncthreads();

    float acc[4][4];
#pragma unroll
    for (int i = 0; i < 4; ++i)
#pragma unroll
        for (int j = 0; j < 4; ++j) acc[i][j] = 0.f;

#pragma unroll
    for (int kk = 0; kk < 64; kk += 4) {
        float4 a4[4];
#pragma unroll
        for (int i = 0; i < 4; ++i)
            a4[i] = *(const float4*)(Af + (ty * 4 + i) * 68 + kk);
#pragma unroll
        for (int k2 = 0; k2 < 4; ++k2) {
            float w[4];
            *(float4*)w = *(const float4*)(Wl + (kk + k2) * 64 + tx * 4);
#pragma unroll
            for (int i = 0; i < 4; ++i) {
                float a = ((const float*)&a4[i])[k2];
#pragma unroll
                for (int j = 0; j < 4; ++j) acc[i][j] = fmaf(a, w[j], acc[i][j]);
            }
        }
    }

    if constexpr (MODE == 1) {
        const float ombeta = 1.f - beta;
#pragma unroll
        for (int i = 0; i < 4; ++i) {
            int ng = base + ty * 4 + i;
            if (ng < n) {
                ushort4 r;
                float s0 = Af[(ty * 4 + i) * 68 + tx * 4 + 0];
                float s1 = Af[(ty * 4 + i) * 68 + tx * 4 + 1];
                float s2 = Af[(ty * 4 + i) * 68 + tx * 4 + 2];
                float s3 = Af[(ty * 4 + i) * 68 + tx * 4 + 3];
                r.x = f2bf(fmaxf(fmaf(beta, acc[i][0], ombeta * s0), 0.f));
                r.y = f2bf(fmaxf(fmaf(beta, acc[i][1], ombeta * s1), 0.f));
                r.z = f2bf(fmaxf(fmaf(beta, acc[i][2], ombeta * s2), 0.f));
                r.w = f2bf(fmaxf(fmaf(beta, acc[i][3], ombeta * s3), 0.f));
                *(ushort4*)(C + (size_t)ng * HD + tx * 4) = r;
            }
        }
    } else {
        float b[4];
#pragma unroll
        for (int j = 0; j < 4; ++j) b[j] = bias[tx * 4 + j];
        const bool valid = (tx < 10);
#pragma unroll
        for (int i = 0; i < 4; ++i) {
            float lo[4];
            float m = -3.0e38f;
#pragma unroll
            for (int j = 0; j < 4; ++j) {
                lo[j] = acc[i][j] + b[j];
                if (valid) m = fmaxf(m, lo[j]);
            }
#pragma unroll
            for (int off = 1; off < 16; off <<= 1)
                m = fmaxf(m, __shfl_xor(m, off, 64));
            float s = 0.f;
            if (valid) {
#pragma unroll
                for (int j = 0; j < 4; ++j) s += __expf(lo[j] - m);
            }
#pragma unroll
            for (int off = 1; off < 16; off <<= 1)
                s += __shfl_xor(s, off, 64);
            float lse = __logf(s);
            int ng = base + ty * 4 + i;
            if (ng < n && valid) {
                float4 r;
                r.x = lo[0] - m - lse; r.y = lo[1] - m - lse;
                r.z = lo[2] - m - lse; r.w = lo[3] - m - lse;
                *(float4*)(outp + (size_t)ng * NC + tx * 4) = r;
            }
        }
    }
}

// ---------------- launch ----------------

extern "C" void kernel_launch(void* const* d_in, const int* in_sizes, int n_in,
                              void* d_out, int out_size, void* d_ws, size_t ws_size,
                              hipStream_t stream) {
    const float* x        = (const float*)d_in[0];
    const int*   eidx     = (const int*)d_in[1];
    const float* ew       = (const float*)d_in[2];
    const float* W_in     = (const float*)d_in[3];
    const float* b_in     = (const float*)d_in[4];
    const float* W_layers = (const float*)d_in[5];
    const float* W_out    = (const float*)d_in[6];
    const float* b_out    = (const float*)d_in[7];
    float* out = (float*)d_out;

    const int N = in_sizes[0] / FIN;
    const int E = in_sizes[2];
    const int L = in_sizes[5] / (HD * HD);
    const int* src = eidx;
    const int* dst = eidx + E;

    size_t off = 0;
    auto carve = [&](size_t bytes) {
        void* p = (char*)d_ws + off;
        off += (bytes + 255) & ~(size_t)255;
        return p;
    };
    unsigned long long* packed8 = (unsigned long long*)carve((size_t)N * 8 * 8);
    float*  dinv    = (float*)carve((size_t)N * 4);
    uint2*  cbase   = (uint2*)carve((size_t)N * 8);
    int*    row_ptr = (int*)  carve((size_t)(N + 1) * 4);
    int*    bsums   = (int*)  carve(512 * 4);
    float*  Wo_pad  = (float*)carve((size_t)HD * HD * 4);
    float*  bo_pad  = (float*)carve((size_t)HD * 4);
    ushort* Wf      = (ushort*)carve((size_t)FIN * HD * 2);
    ushort* rank    = (ushort*)carve((size_t)E * 2);
    EdgeT*  ed      = (EdgeT*)carve((size_t)E * 8);
    ushort* h0      = (ushort*)carve((size_t)N * HD * 2);
    ushort* hA      = (ushort*)carve((size_t)N * HD * 2);
    ushort* hB      = (ushort*)carve((size_t)N * HD * 2);
    (void)ws_size;

    const int NB = (N + 255) / 256;
    const int EB = (E + 255) / 256;

    initp_kernel<<<(8 * N + 255) / 256, 256, 0, stream>>>(packed8, N);
    histp_kernel<<<EB, 256, 0, stream>>>(dst, ew, packed8, rank, E, N);
    post_kernel<<<NB, 256, 0, stream>>>(packed8, dinv, cbase, row_ptr, bsums, N);
    scan_top_kernel<<<1, 512, 0, stream>>>(bsums, NB);
    scan_add_kernel<<<NB, 256, 0, stream>>>(row_ptr, bsums, N, E);
    scatter_kernel<<<EB, 256, 0, stream>>>(src, dst, ew, dinv, row_ptr, cbase, rank, ed, E);
    setup_kernel<<<(FIN * HD + 255) / 256, 256, 0, stream>>>(W_in, Wf, W_out, b_out,
                                                             Wo_pad, bo_pad);

    projm_kernel<<<(N + 127) / 128, 256, 0, stream>>>(x, Wf, b_in, h0, N);

    const int NT = (N + 63) / 64;
    const ushort* cur = h0;
    ushort* bufs[2] = { hA, hB };
    for (int i = 0; i < L; ++i) {
        float beta = logf(0.5f / (float)(i + 1) + 1.0f);
        ushort* sup = bufs[i & 1];
        spmm_kernel<<<2048, 256, 0, stream>>>(cur, h0, sup, dinv, row_ptr, ed, N);
        lgemm_kernel<1><<<NT, 256, 0, stream>>>(sup, W_layers + (size_t)i * HD * HD,
                                                nullptr, sup, nullptr, N, beta);
        cur = sup;
    }

    lgemm_kernel<2><<<NT, 256, 0, stream>>>(cur, Wo_pad, bo_pad, nullptr, out, N, 0.f);
}

// Round 9
// 554.552 us; speedup vs baseline: 1.3853x; 1.0143x over previous
//
#include <hip/hip_runtime.h>
#include <math.h>

#define HD 64
#define FIN 512
#define NC 40

struct __align__(8) EdgeT { int s; float v; };

typedef __attribute__((ext_vector_type(8))) short bf16x8;
typedef __attribute__((ext_vector_type(8))) unsigned short u16x8;
typedef __attribute__((ext_vector_type(4))) float f32x4;

__device__ __forceinline__ float bf2f(ushort u) {
    return __uint_as_float(((unsigned int)u) << 16);
}
__device__ __forceinline__ ushort f2bf(float f) {
    unsigned int u = __float_as_uint(f);
    unsigned int r = (u + 0x7fffu + ((u >> 16) & 1u)) >> 16;   // RNE
    return (ushort)r;
}

// ---------------- graph preprocessing ----------------
// packed8[c*n+i]: bits[48:64) = edge count, bits[0:48) = fixed-point(2^-32) weighted degree.
// 8 shadow copies (c = edge_id & 7) cut atomic contention 8x. Fixed-point sum is order-exact.

__global__ __launch_bounds__(256) void initp_kernel(unsigned long long* packed8, int n) {
    int i = blockIdx.x * 256 + threadIdx.x;
    if (i < 8 * n) packed8[i] = (i < n) ? (1ULL << 32) : 0ULL;  // self-loop w=1 in copy 0
}

__global__ __launch_bounds__(256) void histp_kernel(const int* __restrict__ dst,
        const float* __restrict__ w, unsigned long long* packed8,
        ushort* __restrict__ rank, int E, int n) {
    int i = blockIdx.x * 256 + threadIdx.x;
    if (i < E) {
        int d = dst[i];
        int c = i & 7;
        unsigned long long add = (1ULL << 48) |
            (unsigned long long)(w[i] * 4294967296.0f);
        unsigned long long old = atomicAdd(&packed8[(size_t)c * n + d], add);
        rank[i] = (ushort)(old >> 48);
    }
}

// fused: dinv + copy-bases (8 bytes in uint2) + per-block count scan
__global__ __launch_bounds__(256) void post_kernel(const unsigned long long* __restrict__ packed8,
        float* __restrict__ dinv, uint2* __restrict__ cbase,
        int* __restrict__ row_ptr, int* __restrict__ bsums, int n) {
    __shared__ int s[256];
    const unsigned long long M = 0xFFFFFFFFFFFFULL;
    int t = threadIdx.x;
    int i = blockIdx.x * 256 + t;
    int cnt = 0;
    if (i < n) {
        int c[8];
        unsigned long long fx = 0;
#pragma unroll
        for (int k = 0; k < 8; ++k) {
            unsigned long long p = packed8[(size_t)k * n + i];
            c[k] = (int)(p >> 48);
            fx += (p & M);
        }
        float deg = (float)((double)fx * (1.0 / 4294967296.0));
        dinv[i] = rsqrtf(deg);                     // deg >= 1 (self-loop)
        int b = 0; uint lo = 0, hi = 0;
#pragma unroll
        for (int k = 0; k < 4; ++k) { lo |= ((uint)b) << (8 * k); b += c[k]; }
#pragma unroll
        for (int k = 0; k < 4; ++k) { hi |= ((uint)b) << (8 * k); b += c[4 + k]; }
        cbase[i] = make_uint2(lo, hi);
        cnt = b;
    }
    s[t] = cnt; __syncthreads();
    for (int off = 1; off < 256; off <<= 1) {
        int u = (t >= off) ? s[t - off] : 0;
        __syncthreads();
        s[t] += u;
        __syncthreads();
    }
    if (i < n) row_ptr[i] = s[t] - cnt;
    if (t == 255) bsums[blockIdx.x] = s[255];
}

__global__ __launch_bounds__(512) void scan_top_kernel(int* bsums, int nb) {
    __shared__ int s[512];
    int t = threadIdx.x;
    int v = (t < nb) ? bsums[t] : 0;
    s[t] = v; __syncthreads();
    for (int off = 1; off < 512; off <<= 1) {
        int u = (t >= off) ? s[t - off] : 0;
        __syncthreads();
        s[t] += u;
        __syncthreads();
    }
    if (t < nb) bsums[t] = s[t] - v;
}

__global__ __launch_bounds__(256) void scan_add_kernel(int* __restrict__ row_ptr,
        const int* __restrict__ bsums, int n, int E) {
    int i = blockIdx.x * 256 + threadIdx.x;
    if (i < n) row_ptr[i] += bsums[blockIdx.x];
    if (i == 0) row_ptr[n] = E;
}

__global__ __launch_bounds__(256) void scatter_kernel(const int* __restrict__ src,
        const int* __restrict__ dst, const float* __restrict__ w,
        const float* __restrict__ dinv, const int* __restrict__ row_ptr,
        const uint2* __restrict__ cbase, const ushort* __restrict__ rank,
        EdgeT* __restrict__ ed, int E) {
    int i = blockIdx.x * 256 + threadIdx.x;
    if (i < E) {
        int s = src[i], d = dst[i];
        int c = i & 7;
        uint2 cb = cbase[d];
        int base = (int)(((c < 4) ? (cb.x >> (8 * c)) : (cb.y >> (8 * (c - 4)))) & 0xffu);
        int pos = row_ptr[d] + base + (int)rank[i];
        EdgeT e; e.s = s; e.v = dinv[s] * w[i] * dinv[d];
        ed[pos] = e;
    }
}

// setup: W_out zero-pad + b_out pad + W_in -> bf16 fragment-major
// Wf[((c*4+t)*64+l)*8+j] = W_in[c*32+8*(l>>4)+j][t*16+(l&15)]
__global__ __launch_bounds__(256) void setup_kernel(const float* __restrict__ W,
        ushort* __restrict__ Wf, const float* __restrict__ Wo,
        const float* __restrict__ bo, float* __restrict__ Wo_pad,
        float* __restrict__ bo_pad) {
    int i = blockIdx.x * 256 + threadIdx.x;
    if (i < FIN * HD) {
        int j = i & 7;
        int l = (i >> 3) & 63;
        int t = (i >> 9) & 3;
        int c = i >> 11;
        int k = c * 32 + ((l >> 4) * 8) + j;
        int col = t * 16 + (l & 15);
        Wf[i] = f2bf(W[k * HD + col]);
    }
    if (i < HD * HD) {
        int k = i >> 6, c2 = i & 63;
        Wo_pad[i] = (c2 < NC) ? Wo[k * NC + c2] : 0.f;
    }
    if (i < HD) bo_pad[i] = (i < NC) ? bo[i] : 0.f;
}

// ---------------- SpMM v4 (bf16 h, 8 nodes/wave): agg = Ahat @ h_in ----------------
// 8 lanes per node; lane owns feature octet (lane&7)*8 (16B loads). Residual applied
// later in lgemm staging (keeps this latency-bound kernel lean).

__global__ __launch_bounds__(256) void spmm_kernel(const ushort* __restrict__ h_in,
        ushort* __restrict__ agg, const float* __restrict__ dinv,
        const int* __restrict__ row_ptr, const EdgeT* __restrict__ ed, int n) {
    const int lane = threadIdx.x & 63;
    const int g = lane >> 3;               // node slot 0..7
    const int fl = (lane & 7) * 8;         // feature offset
    int oct = (blockIdx.x * 256 + threadIdx.x) >> 6;
    int node = oct * 8 + g;
    bool valid = node < n;
    int nc = valid ? node : n - 1;

    float di = dinv[nc];
    float sw = di * di;
    u16x8 us = *(const u16x8*)(h_in + (size_t)nc * HD + fl);
    float a[8], b[8];
#pragma unroll
    for (int j = 0; j < 8; ++j) { a[j] = sw * bf2f((ushort)us[j]); b[j] = 0.f; }

    int e = row_ptr[nc], end = row_ptr[nc + 1];
    for (; e + 4 <= end; e += 4) {
        EdgeT E0 = ed[e], E1 = ed[e + 1], E2 = ed[e + 2], E3 = ed[e + 3];
        u16x8 u0 = *(const u16x8*)(h_in + (size_t)E0.s * HD + fl);
        u16x8 u1 = *(const u16x8*)(h_in + (size_t)E1.s * HD + fl);
        u16x8 u2 = *(const u16x8*)(h_in + (size_t)E2.s * HD + fl);
        u16x8 u3 = *(const u16x8*)(h_in + (size_t)E3.s * HD + fl);
#pragma unroll
        for (int j = 0; j < 8; ++j) {
            a[j] = fmaf(E0.v, bf2f((ushort)u0[j]), a[j]);
            b[j] = fmaf(E1.v, bf2f((ushort)u1[j]), b[j]);
            a[j] = fmaf(E2.v, bf2f((ushort)u2[j]), a[j]);
            b[j] = fmaf(E3.v, bf2f((ushort)u3[j]), b[j]);
        }
    }
    for (; e < end; ++e) {
        EdgeT E0 = ed[e];
        u16x8 u0 = *(const u16x8*)(h_in + (size_t)E0.s * HD + fl);
#pragma unroll
        for (int j = 0; j < 8; ++j) a[j] = fmaf(E0.v, bf2f((ushort)u0[j]), a[j]);
    }

    if (valid) {
        u16x8 r;
#pragma unroll
        for (int j = 0; j < 8; ++j) r[j] = f2bf(a[j] + b[j]);
        *(u16x8*)(agg + (size_t)node * HD + fl) = r;
    }
}

// ---------------- proj (MFMA): h0 = relu(x @ W_in + b_in) -> bf16 ----------------
// wave: 32 nodes (2 M-frags) x 64 cols (4 N-frags); block = 4 waves = 128 nodes.

__global__ __launch_bounds__(256) void projm_kernel(const float* __restrict__ x,
        const ushort* __restrict__ Wf, const float* __restrict__ bias,
        ushort* __restrict__ h0, int n) {
    const int lane = threadIdx.x & 63;
    const int wave = threadIdx.x >> 6;
    const int row = lane & 15;
    const int g = lane >> 4;
    const int base = blockIdx.x * 128 + wave * 32;

    f32x4 acc[2][4];
#pragma unroll
    for (int m = 0; m < 2; ++m)
#pragma unroll
        for (int t = 0; t < 4; ++t) acc[m][t] = (f32x4){0.f, 0.f, 0.f, 0.f};

    for (int c = 0; c < 16; ++c) {
        bf16x8 afr[2];
#pragma unroll
        for (int m = 0; m < 2; ++m) {
            int node = base + m * 16 + row;
            if (node >= n) node = n - 1;
            const float* p = x + (size_t)node * FIN + c * 32 + g * 8;
            float4 v0 = *(const float4*)p;
            float4 v1 = *(const float4*)(p + 4);
            afr[m][0] = (short)f2bf(v0.x); afr[m][1] = (short)f2bf(v0.y);
            afr[m][2] = (short)f2bf(v0.z); afr[m][3] = (short)f2bf(v0.w);
            afr[m][4] = (short)f2bf(v1.x); afr[m][5] = (short)f2bf(v1.y);
            afr[m][6] = (short)f2bf(v1.z); afr[m][7] = (short)f2bf(v1.w);
        }
#pragma unroll
        for (int t = 0; t < 4; ++t) {
            bf16x8 bfr = *(const bf16x8*)(Wf + ((size_t)(c * 4 + t) * 64 + lane) * 8);
            acc[0][t] = __builtin_amdgcn_mfma_f32_16x16x32_bf16(afr[0], bfr, acc[0][t], 0, 0, 0);
            acc[1][t] = __builtin_amdgcn_mfma_f32_16x16x32_bf16(afr[1], bfr, acc[1][t], 0, 0, 0);
        }
    }

    float bj[4];
#pragma unroll
    for (int t = 0; t < 4; ++t) bj[t] = bias[t * 16 + row];
#pragma unroll
    for (int m = 0; m < 2; ++m)
#pragma unroll
        for (int r = 0; r < 4; ++r) {
            int node = base + m * 16 + g * 4 + r;
            if (node < n) {
#pragma unroll
                for (int t = 0; t < 4; ++t) {
                    float v = fmaxf(acc[m][t][r] + bj[t], 0.f);
                    h0[(size_t)node * HD + t * 16 + row] = f2bf(v);
                }
            }
        }
}

// ---------------- layer / output GEMM over bf16 A, fp32 W, K=64 ----------------
// MODE 1: Af = 0.9*agg + 0.1*h0 (f32); C = relu(beta*(Af@W) + (1-beta)*Af) -> bf16
// MODE 2: log_softmax(A@W + bias) over first NC cols -> outp fp32

template<int MODE>
__global__ __launch_bounds__(256) void lgemm_kernel(const ushort* __restrict__ A,
        const ushort* __restrict__ h0r, const float* __restrict__ W,
        const float* __restrict__ bias, ushort* __restrict__ C,
        float* __restrict__ outp, int n, float beta) {
    __shared__ float Af[64 * 68];
    __shared__ float Wl[64 * 64];
    const int tid = threadIdx.x;
    const int tx = tid & 15;
    const int ty = tid >> 4;
    const int base = blockIdx.x * 64;
    const int kq = (tid & 15) * 4;
    const int rw = tid >> 4;

#pragma unroll
    for (int p = 0; p < 4; ++p) {
        int row = rw + p * 16;
        int ng = base + row; if (ng >= n) ng = n - 1;
        ushort4 u = *(const ushort4*)(A + (size_t)ng * HD + kq);
        if constexpr (MODE == 1) {
            ushort4 uh = *(const ushort4*)(h0r + (size_t)ng * HD + kq);
            Af[row * 68 + kq + 0] = fmaf(0.9f, bf2f(u.x), 0.1f * bf2f(uh.x));
            Af[row * 68 + kq + 1] = fmaf(0.9f, bf2f(u.y), 0.1f * bf2f(uh.y));
            Af[row * 68 + kq + 2] = fmaf(0.9f, bf2f(u.z), 0.1f * bf2f(uh.z));
            Af[row * 68 + kq + 3] = fmaf(0.9f, bf2f(u.w), 0.1f * bf2f(uh.w));
        } else {
            Af[row * 68 + kq + 0] = bf2f(u.x);
            Af[row * 68 + kq + 1] = bf2f(u.y);
            Af[row * 68 + kq + 2] = bf2f(u.z);
            Af[row * 68 + kq + 3] = bf2f(u.w);
        }
        *(float4*)(Wl + row * 64 + kq) =
            *(const float4*)(W + (size_t)row * HD + kq);
    }
    __syncthreads();

    float acc[4][4];
#pragma unroll
    for (int i = 0; i < 4; ++i)
#pragma unroll
        for (int j = 0; j < 4; ++j) acc[i][j] = 0.f;

#pragma unroll
    for (int kk = 0; kk < 64; kk += 4) {
        float4 a4[4];
#pragma unroll
        for (int i = 0; i < 4; ++i)
            a4[i] = *(const float4*)(Af + (ty * 4 + i) * 68 + kk);
#pragma unroll
        for (int k2 = 0; k2 < 4; ++k2) {
            float w[4];
            *(float4*)w = *(const float4*)(Wl + (kk + k2) * 64 + tx * 4);
#pragma unroll
            for (int i = 0; i < 4; ++i) {
                float a = ((const float*)&a4[i])[k2];
#pragma unroll
                for (int j = 0; j < 4; ++j) acc[i][j] = fmaf(a, w[j], acc[i][j]);
            }
        }
    }

    if constexpr (MODE == 1) {
        const float ombeta = 1.f - beta;
#pragma unroll
        for (int i = 0; i < 4; ++i) {
            int ng = base + ty * 4 + i;
            if (ng < n) {
                ushort4 r;
                float s0 = Af[(ty * 4 + i) * 68 + tx * 4 + 0];
                float s1 = Af[(ty * 4 + i) * 68 + tx * 4 + 1];
                float s2 = Af[(ty * 4 + i) * 68 + tx * 4 + 2];
                float s3 = Af[(ty * 4 + i) * 68 + tx * 4 + 3];
                r.x = f2bf(fmaxf(fmaf(beta, acc[i][0], ombeta * s0), 0.f));
                r.y = f2bf(fmaxf(fmaf(beta, acc[i][1], ombeta * s1), 0.f));
                r.z = f2bf(fmaxf(fmaf(beta, acc[i][2], ombeta * s2), 0.f));
                r.w = f2bf(fmaxf(fmaf(beta, acc[i][3], ombeta * s3), 0.f));
                *(ushort4*)(C + (size_t)ng * HD + tx * 4) = r;
            }
        }
    } else {
        float b[4];
#pragma unroll
        for (int j = 0; j < 4; ++j) b[j] = bias[tx * 4 + j];
        const bool valid = (tx < 10);
#pragma unroll
        for (int i = 0; i < 4; ++i) {
            float lo[4];
            float m = -3.0e38f;
#pragma unroll
            for (int j = 0; j < 4; ++j) {
                lo[j] = acc[i][j] + b[j];
                if (valid) m = fmaxf(m, lo[j]);
            }
#pragma unroll
            for (int off = 1; off < 16; off <<= 1)
                m = fmaxf(m, __shfl_xor(m, off, 64));
            float s = 0.f;
            if (valid) {
#pragma unroll
                for (int j = 0; j < 4; ++j) s += __expf(lo[j] - m);
            }
#pragma unroll
            for (int off = 1; off < 16; off <<= 1)
                s += __shfl_xor(s, off, 64);
            float lse = __logf(s);
            int ng = base + ty * 4 + i;
            if (ng < n && valid) {
                float4 r;
                r.x = lo[0] - m - lse; r.y = lo[1] - m - lse;
                r.z = lo[2] - m - lse; r.w = lo[3] - m - lse;
                *(float4*)(outp + (size_t)ng * NC + tx * 4) = r;
            }
        }
    }
}

// ---------------- launch ----------------

extern "C" void kernel_launch(void* const* d_in, const int* in_sizes, int n_in,
                              void* d_out, int out_size, void* d_ws, size_t ws_size,
                              hipStream_t stream) {
    const float* x        = (const float*)d_in[0];
    const int*   eidx     = (const int*)d_in[1];
    const float* ew       = (const float*)d_in[2];
    const float* W_in     = (const float*)d_in[3];
    const float* b_in     = (const float*)d_in[4];
    const float* W_layers = (const float*)d_in[5];
    const float* W_out    = (const float*)d_in[6];
    const float* b_out    = (const float*)d_in[7];
    float* out = (float*)d_out;

    const int N = in_sizes[0] / FIN;
    const int E = in_sizes[2];
    const int L = in_sizes[5] / (HD * HD);
    const int* src = eidx;
    const int* dst = eidx + E;

    size_t off = 0;
    auto carve = [&](size_t bytes) {
        void* p = (char*)d_ws + off;
        off += (bytes + 255) & ~(size_t)255;
        return p;
    };
    unsigned long long* packed8 = (unsigned long long*)carve((size_t)N * 8 * 8);
    float*  dinv    = (float*)carve((size_t)N * 4);
    uint2*  cbase   = (uint2*)carve((size_t)N * 8);
    int*    row_ptr = (int*)  carve((size_t)(N + 1) * 4);
    int*    bsums   = (int*)  carve(512 * 4);
    float*  Wo_pad  = (float*)carve((size_t)HD * HD * 4);
    float*  bo_pad  = (float*)carve((size_t)HD * 4);
    ushort* Wf      = (ushort*)carve((size_t)FIN * HD * 2);
    ushort* rank    = (ushort*)carve((size_t)E * 2);
    EdgeT*  ed      = (EdgeT*)carve((size_t)E * 8);
    ushort* h0      = (ushort*)carve((size_t)N * HD * 2);
    ushort* hA      = (ushort*)carve((size_t)N * HD * 2);
    ushort* hB      = (ushort*)carve((size_t)N * HD * 2);
    (void)ws_size;

    const int NB = (N + 255) / 256;
    const int EB = (E + 255) / 256;

    initp_kernel<<<(8 * N + 255) / 256, 256, 0, stream>>>(packed8, N);
    histp_kernel<<<EB, 256, 0, stream>>>(dst, ew, packed8, rank, E, N);
    post_kernel<<<NB, 256, 0, stream>>>(packed8, dinv, cbase, row_ptr, bsums, N);
    scan_top_kernel<<<1, 512, 0, stream>>>(bsums, NB);
    scan_add_kernel<<<NB, 256, 0, stream>>>(row_ptr, bsums, N, E);
    scatter_kernel<<<EB, 256, 0, stream>>>(src, dst, ew, dinv, row_ptr, cbase, rank, ed, E);
    setup_kernel<<<(FIN * HD + 255) / 256, 256, 0, stream>>>(W_in, Wf, W_out, b_out,
                                                             Wo_pad, bo_pad);

    projm_kernel<<<(N + 127) / 128, 256, 0, stream>>>(x, Wf, b_in, h0, N);

    const int NT = (N + 63) / 64;
    const int nocts = (N + 7) / 8;
    const int SB = (nocts + 3) / 4;        // 4 waves/block, 1 oct/wave
    const ushort* cur = h0;
    ushort* bufs[2] = { hA, hB };
    for (int i = 0; i < L; ++i) {
        float beta = logf(0.5f / (float)(i + 1) + 1.0f);
        ushort* sup = bufs[i & 1];
        spmm_kernel<<<SB, 256, 0, stream>>>(cur, sup, dinv, row_ptr, ed, N);
        lgemm_kernel<1><<<NT, 256, 0, stream>>>(sup, h0, W_layers + (size_t)i * HD * HD,
                                                nullptr, sup, nullptr, N, beta);
        cur = sup;
    }

    lgemm_kernel<2><<<NT, 256, 0, stream>>>(cur, nullptr, Wo_pad, bo_pad, nullptr, out, N, 0.f);
}